// Round 4
// baseline (321.736 us; speedup 1.0000x reference)
//
#include <hip/hip_runtime.h>
#include <hip/hip_bf16.h>
#include <stdint.h>

// VectorQuantization: out[n] = codebook[argmax_k dot(x[n], codebook[k])]
// (L2-normalize is a positive row-scalar -> argmax-invariant -> skipped)
//
// R4 strategy: MX-scaled fp8 e4m3 MFMA (16x16x128 f8f6f4, unit e8m0 scales,
// 2x bf16 rate, 4x K-depth per instruction) for the approx-sims GEMM.
// Codebook pre-scaled x64 before fp8 conversion (sigma=0.01 would land in
// e4m3 subnormals; x64 -> normal range; argmax scale-invariant; all approx
// sims/margins live at 64x scale). fp8 sim-diff error std ~8e-3 -> NSPLIT=64
// top-2/split candidates + MARGIN=3.2 (=0.05 true scale, ~6 sigma) flagging
// + exact fp64 recheck from original fp32 inputs.
//
// Carried: zero-conflict XOR swizzle (R2: 3.35e7 -> 0), adapted to 128B rows.

typedef float f32x4 __attribute__((ext_vector_type(4)));
typedef int int4v __attribute__((ext_vector_type(4)));
typedef int int8v __attribute__((ext_vector_type(8)));

#define M_ROWS 8192
#define DIM 512
#define K_CODES 16384
#define BM 128
#define BN 128
#define BK 128                      /* fp8 elements (bytes) per k-step */
#define NSPLIT 64
#define NT ((K_CODES / NSPLIT) / BN) /* 2 */
#define NEG_INF (-3.402823466e+38f)
#define MARGIN 3.2f                 /* 0.05 in true sim scale (x64) */
#define CB_SCALE 64.0f
#define N4X (M_ROWS * DIM / 4)
#define N4C (K_CODES * DIM / 4)

typedef __attribute__((address_space(1))) uint32_t as1_u32;
typedef __attribute__((address_space(3))) uint32_t as3_u32;

__device__ __forceinline__ void gll16(const void* g, void* l) {
  // async global->LDS, 16B/lane; LDS dest = wave-uniform base + lane*16
  __builtin_amdgcn_global_load_lds((const as1_u32*)(uintptr_t)g,
                                   (as3_u32*)(uintptr_t)l, 16, 0, 0);
}

// stage a [128 rows x 128 B] fp8 tile (16 KB) from row-major [*, DIM] source.
// swizzled: LDS slot s (16B chunks) holds chunk (row=s>>3, kc=(s&7)^(row&7)).
__device__ __forceinline__ void stage_tile_fp8(const uint8_t* __restrict__ g_base,
                                               uint8_t* lds_tile, int tid) {
#pragma unroll
  for (int r = 0; r < 4; ++r) {
    const int s = r * 256 + tid;
    const int row = s >> 3;
    const int kc = (s & 7) ^ (row & 7);
    const uint8_t* g = g_base + (size_t)row * DIM + (kc << 4);
    uint8_t* l = lds_tile + ((size_t)(r * 256 + (tid & 192)) << 4);
    gll16((const void*)g, (void*)l);
  }
}

// fused fp32 -> e4m3 conversion: blocks [0, N4X/256) convert x (scale 1),
// the rest convert codebook (scale 64).
__global__ void cvt_fp8(const float* __restrict__ x, const float* __restrict__ cb,
                        uint8_t* __restrict__ xd, uint8_t* __restrict__ cd) {
  int i = blockIdx.x * 256 + threadIdx.x;
  const float* src;
  uint8_t* dst;
  float sc;
  if (i < N4X) {
    src = x; dst = xd; sc = 1.0f;
  } else {
    src = cb; dst = cd; sc = CB_SCALE; i -= N4X;
    if (i >= N4C) return;
  }
  const float4 v = reinterpret_cast<const float4*>(src)[i];
  int w = 0;
  w = __builtin_amdgcn_cvt_pk_fp8_f32(v.x * sc, v.y * sc, w, false);
  w = __builtin_amdgcn_cvt_pk_fp8_f32(v.z * sc, v.w * sc, w, true);
  reinterpret_cast<int*>(dst)[i] = w;
}

__global__ __launch_bounds__(256, 2) void vq_argmax(
    const uint8_t* __restrict__ xq, const uint8_t* __restrict__ cq,
    float* __restrict__ pv, int* __restrict__ pi) {
  __shared__ __align__(16) uint8_t sxa[BM * BK];   // 16 KB
  __shared__ __align__(16) uint8_t scb[BN * BK];   // 16 KB
  __shared__ float rv1[2][BM], rv2[2][BM];
  __shared__ int ri1[2][BM], ri2[2][BM];

  const int tid = threadIdx.x;
  const int w = tid >> 6, lane = tid & 63;
  const int wm = w & 1, wn = w >> 1;        // 2x2 wave grid over 128x128 tile
  const int l15 = lane & 15, quad = lane >> 4;
  const int row0 = blockIdx.x * BM;
  const int split = blockIdx.y;
  const int n_base = split * (K_CODES / NSPLIT);
  const int sw = l15 & 7;                   // frag rows are base+l15, base%16==0

  float bv1[4][4], bv2[4][4];
  int bi1[4][4], bi2[4][4];
#pragma unroll
  for (int i = 0; i < 4; ++i)
#pragma unroll
    for (int r = 0; r < 4; ++r) {
      bv1[i][r] = NEG_INF; bv2[i][r] = NEG_INF;
      bi1[i][r] = 0x7fffffff; bi2[i][r] = 0x7fffffff;
    }

#pragma unroll 1
  for (int nt = 0; nt < NT; ++nt) {
    const int n0 = n_base + nt * BN;
    f32x4 acc[4][4];
#pragma unroll
    for (int i = 0; i < 4; ++i)
#pragma unroll
      for (int j = 0; j < 4; ++j) acc[i][j] = (f32x4){0.f, 0.f, 0.f, 0.f};

#pragma unroll 1
    for (int ks = 0; ks < DIM / BK; ++ks) {   // 4 k-steps
      const int k0 = ks * BK;
      stage_tile_fp8(xq + (size_t)row0 * DIM + k0, sxa, tid);
      stage_tile_fp8(cq + (size_t)n0 * DIM + k0, scb, tid);
      __syncthreads();

      int8v A[4], B[4];
#pragma unroll
      for (int i = 0; i < 4; ++i) {
        // A frag: m = lane&15, k = quad*32 + j (32 contiguous fp8 bytes);
        // swizzled chunk slots (quad*2+c) ^ sw, c = 0,1
        const int ra = (wm * 64 + i * 16 + l15) * BK;
        const int rb = (wn * 64 + i * 16 + l15) * BK;
        int4v alo = *(const int4v*)&sxa[ra + ((((quad << 1) | 0) ^ sw) << 4)];
        int4v ahi = *(const int4v*)&sxa[ra + ((((quad << 1) | 1) ^ sw) << 4)];
        int4v blo = *(const int4v*)&scb[rb + ((((quad << 1) | 0) ^ sw) << 4)];
        int4v bhi = *(const int4v*)&scb[rb + ((((quad << 1) | 1) ^ sw) << 4)];
        A[i] = __builtin_shufflevector(alo, ahi, 0, 1, 2, 3, 4, 5, 6, 7);
        B[i] = __builtin_shufflevector(blo, bhi, 0, 1, 2, 3, 4, 5, 6, 7);
      }
#pragma unroll
      for (int i = 0; i < 4; ++i)
#pragma unroll
        for (int j = 0; j < 4; ++j)
          acc[i][j] = __builtin_amdgcn_mfma_scale_f32_16x16x128_f8f6f4(
              A[i], B[j], acc[i][j], 0 /*cbsz: fp8*/, 0 /*blgp: fp8*/,
              0, 0x7F7F7F7F /*scale_a = 1.0 (e8m0 127)*/,
              0, 0x7F7F7F7F /*scale_b = 1.0*/);
      __syncthreads();
    }

    // per-lane running top-2 (ascending index order -> strict > keeps lowest)
    // C/D layout: row = i*16 + quad*4 + r, col = j*16 + (lane&15)
#pragma unroll
    for (int i = 0; i < 4; ++i)
#pragma unroll
      for (int r = 0; r < 4; ++r)
#pragma unroll
        for (int j = 0; j < 4; ++j) {
          float s = acc[i][j][r];
          int c = n0 + wn * 64 + j * 16 + l15;
          if (s > bv1[i][r]) {
            bv2[i][r] = bv1[i][r]; bi2[i][r] = bi1[i][r];
            bv1[i][r] = s; bi1[i][r] = c;
          } else if (s > bv2[i][r]) {
            bv2[i][r] = s; bi2[i][r] = c;
          }
        }
  }

  // butterfly-merge top-2 across the 16 lanes (columns) of each quad
#pragma unroll
  for (int i = 0; i < 4; ++i)
#pragma unroll
    for (int r = 0; r < 4; ++r) {
      float a1 = bv1[i][r], a2 = bv2[i][r];
      int x1 = bi1[i][r], x2 = bi2[i][r];
#pragma unroll
      for (int d = 1; d < 16; d <<= 1) {
        float b1 = __shfl_xor(a1, d), b2 = __shfl_xor(a2, d);
        int y1 = __shfl_xor(x1, d), y2 = __shfl_xor(x2, d);
        bool bw = (b1 > a1) || (b1 == a1 && y1 < x1);
        float w1 = bw ? b1 : a1;  int wi = bw ? y1 : x1;
        float l1 = bw ? a1 : b1;  int li = bw ? x1 : y1;
        float s2 = bw ? b2 : a2;  int si = bw ? y2 : x2;
        bool t = (s2 > l1) || (s2 == l1 && si < li);
        a1 = w1; x1 = wi;
        a2 = t ? s2 : l1; x2 = t ? si : li;
      }
      bv1[i][r] = a1; bi1[i][r] = x1; bv2[i][r] = a2; bi2[i][r] = x2;
    }

  if (l15 == 0) {
#pragma unroll
    for (int i = 0; i < 4; ++i)
#pragma unroll
      for (int r = 0; r < 4; ++r) {
        const int rl = wm * 64 + i * 16 + quad * 4 + r;
        rv1[wn][rl] = bv1[i][r]; ri1[wn][rl] = bi1[i][r];
        rv2[wn][rl] = bv2[i][r]; ri2[wn][rl] = bi2[i][r];
      }
  }
  __syncthreads();
  if (tid < BM) {
    float a1 = rv1[0][tid], a2 = rv2[0][tid];
    int x1 = ri1[0][tid], x2 = ri2[0][tid];
    float b1 = rv1[1][tid], b2 = rv2[1][tid];
    int y1 = ri1[1][tid], y2 = ri2[1][tid];
    bool bw = (b1 > a1) || (b1 == a1 && y1 < x1);
    float w1 = bw ? b1 : a1;  int wi = bw ? y1 : x1;
    float l1 = bw ? a1 : b1;  int li = bw ? x1 : y1;
    float s2 = bw ? b2 : a2;  int si = bw ? y2 : x2;
    bool t = (s2 > l1) || (s2 == l1 && si < li);
    float m2 = t ? s2 : l1;  int mi2 = t ? si : li;
    // partial layout: [row][split*2 + rank], NSPLIT*2 = 128 per row
    const size_t o = (size_t)(row0 + tid) * (NSPLIT * 2) + split * 2;
    pv[o] = w1; pi[o] = wi;
    pv[o + 1] = m2; pi[o + 1] = mi2;
  }
}

__device__ double dot64(const float* __restrict__ a, const float* __restrict__ b) {
  double s0 = 0, s1 = 0, s2 = 0, s3 = 0;
#pragma unroll 4
  for (int t = 0; t < DIM; t += 4) {
    const float4 u = *(const float4*)(a + t);
    const float4 v = *(const float4*)(b + t);
    s0 += (double)u.x * v.x; s1 += (double)u.y * v.y;
    s2 += (double)u.z * v.z; s3 += (double)u.w * v.w;
  }
  return (s0 + s1) + (s2 + s3);
}

__global__ void recheck_gather(const float* __restrict__ pv, const int* __restrict__ pi,
                               const float* __restrict__ x, const float* __restrict__ cb,
                               float* __restrict__ out) {
  const int row = blockIdx.x;
  const int lane = threadIdx.x;   // 64 lanes, 2 candidates each (128 total)
  const size_t base = (size_t)row * (NSPLIT * 2);
  float v0 = pv[base + lane];      int c0 = pi[base + lane];
  float v1 = pv[base + 64 + lane]; int c1 = pi[base + 64 + lane];

  // wave max with lowest-index tie-break
  bool b = (v1 > v0) || (v1 == v0 && c1 < c0);
  float m1 = b ? v1 : v0; int mi1 = b ? c1 : c0;
#pragma unroll
  for (int d = 1; d < 64; d <<= 1) {
    float ov = __shfl_xor(m1, d);
    int oi = __shfl_xor(mi1, d);
    if (ov > m1 || (ov == m1 && oi < mi1)) { m1 = ov; mi1 = oi; }
  }

  const bool f0 = (v0 >= m1 - MARGIN);
  const bool f1 = (v1 >= m1 - MARGIN);
  const int nf = __popcll(__ballot(f0)) + __popcll(__ballot(f1));
  int winner;
  if (nf == 1) {
    winner = mi1;   // approx winner clear of every other candidate by >=6 sigma
  } else {
    // exact fp64 dots from original fp32 inputs for flagged candidates
    const float* xr = x + (size_t)row * DIM;
    double e = -1.0e300; int ei = 0x7fffffff;
    if (f0) { e = dot64(xr, cb + (size_t)c0 * DIM); ei = c0; }
    if (f1) {
      double e2 = dot64(xr, cb + (size_t)c1 * DIM);
      if (e2 > e || (e2 == e && c1 < ei)) { e = e2; ei = c1; }
    }
#pragma unroll
    for (int d = 1; d < 64; d <<= 1) {
      double oe = __shfl_xor(e, d);
      int oi = __shfl_xor(ei, d);
      if (oe > e || (oe == e && oi < ei)) { e = oe; ei = oi; }
    }
    winner = ei;
  }

  const float4* src = (const float4*)(cb + (size_t)winner * DIM);
  float4* dst = (float4*)(out + (size_t)row * DIM);
  dst[lane] = src[lane];         // 512 f32 = 128 float4, 64 lanes x 2
  dst[lane + 64] = src[lane + 64];
}

extern "C" void kernel_launch(void* const* d_in, const int* in_sizes, int n_in,
                              void* d_out, int out_size, void* d_ws, size_t ws_size,
                              hipStream_t stream) {
  const float* x = (const float*)d_in[0];
  const float* cb = (const float*)d_in[1];
  float* out = (float*)d_out;

  // ws layout: x_fp8(4MB) cb_fp8(8MB) pv(4MB) pi(4MB)
  uint8_t* xq = (uint8_t*)d_ws;
  uint8_t* cq = xq + (size_t)M_ROWS * DIM;
  float* pv = (float*)(cq + (size_t)K_CODES * DIM);
  int* pi = (int*)(pv + (size_t)M_ROWS * NSPLIT * 2);

  cvt_fp8<<<(N4X + N4C + 255) / 256, 256, 0, stream>>>(x, cb, xq, cq);
  vq_argmax<<<dim3(M_ROWS / BM, NSPLIT), 256, 0, stream>>>(xq, cq, pv, pi);
  recheck_gather<<<M_ROWS, 64, 0, stream>>>(pv, pi, x, cb, out);
}